// Round 1
// baseline (1696.347 us; speedup 1.0000x reference)
//
#include <hip/hip_runtime.h>

// Q4_0 quantized linear: out[16, 11008] = x[16, 4096] @ ((w_q-8)*w_scale).T + bias
// All fp32; w_q holds int32 nibble values in [0,16).
//
// R=2 row-blocked split-K GEMV with register-prefetched staging.
// vs previous (R=4, 352 blocks, 110 us kernel, 15% occupancy):
//  - 512 rows/block -> grid 22x32 = 704 blocks = 2.75 blocks/CU (was 1.375).
//    LDS 28 KiB (was 47 KiB) so residency is grid/VGPR-limited, not LDS.
//  - w-tile staging is software-pipelined: all 16 int4 loads for sub+1 are
//    issued into registers right after the commit barrier, so their ~900 cyc
//    HBM latency hides under sub's 2.3k-cycle compute phase. Pack+ds_write
//    happens after the next barrier (T14 async-stage split).
// Everything else unchanged: w packed to BYTES in LDS (row stride 36 B ->
// 2-way bank aliasing = free), x chunk staged transposed for broadcast
// float4 reads, fp32 atomicAdd split-K combine, bias added by split 0.

constexpr int T       = 16;
constexpr int IN      = 4096;
constexpr int OUT     = 11008;
constexpr int NSCALE  = IN / 32;        // 128 scales per row
constexpr int THREADS = 256;
constexpr int R       = 2;              // rows per thread
constexpr int ROWSB   = THREADS * R;    // 512 rows per block
constexpr int CK      = 128;            // k per block (split-K chunk)
constexpr int WSUB    = 32;             // k per stage (== Q4_0 block size)
constexpr int NSUB    = CK / WSUB;      // 4
constexpr int WSTRIDE = 36;             // ws8 row stride bytes (32 + 4 pad -> 9 words)
constexpr int XPAD    = 20;             // xs row stride floats (80 B, 16B-aligned)
constexpr int LD4     = (ROWSB * WSUB / 4) / THREADS;  // 16 int4 loads/thread/sub

__global__ __launch_bounds__(THREADS) void qlinear_r2(
    const float* __restrict__ x,        // [T, IN]
    const int*   __restrict__ w_q,      // [OUT, IN]
    const float* __restrict__ w_scale,  // [OUT, NSCALE]
    const float* __restrict__ bias,     // [OUT]
    float* __restrict__ out)            // [T, OUT] (pre-zeroed)
{
    __shared__ __align__(16) float         xs[CK][XPAD];         // 10.0 KiB
    __shared__ __align__(16) unsigned char ws8[ROWSB * WSTRIDE]; // 18.0 KiB

    const int tid  = threadIdx.x;
    const int row0 = blockIdx.x * ROWSB;
    const int k0   = blockIdx.y * CK;

    // ---- stage x chunk transposed: xs[k][t] = x[t][k0+k] (coalesced) ----
    #pragma unroll
    for (int it = 0; it < CK * T / THREADS; ++it) {  // 8
        int idx = it * THREADS + tid;
        int t   = idx >> 7;          // idx / CK
        int k   = idx & (CK - 1);
        xs[k][t] = x[t * IN + k0 + k];
    }

    // w-tile mapping: flat int4 id f = it*256+tid -> row rr = f>>3 = (tid>>3)+32*it,
    // int column j = tid&7 (constant per thread). Lanes 0..7 cover 128
    // contiguous bytes of one row -> fully coalesced dwordx4 loads.
    const int rbase = tid >> 3;
    const int jcol  = (tid & 7) * 4;   // in ints for global, in bytes for LDS

    // ---- per-row scales for the 4 sub-blocks of this k-chunk ----
    float4 sc[R];
    #pragma unroll
    for (int r = 0; r < R; ++r) {
        int rg = min(row0 + tid + r * THREADS, OUT - 1);
        sc[r] = *(const float4*)(w_scale + rg * NSCALE + (k0 >> 5));
    }

    float acc[R][T];
    #pragma unroll
    for (int r = 0; r < R; ++r)
        #pragma unroll
        for (int t = 0; t < T; ++t) acc[r][t] = 0.0f;

    // ---- prefetch sub 0's w tile into registers ----
    int4 v[LD4];
    #pragma unroll
    for (int it = 0; it < LD4; ++it) {
        int rg = min(row0 + rbase + it * 32, OUT - 1);
        v[it] = *(const int4*)(w_q + rg * IN + k0 + jcol);
    }

    #pragma unroll
    for (int sub = 0; sub < NSUB; ++sub) {           // 4
        __syncthreads();   // ws8 drained by all waves (covers xs on first trip)

        // ---- commit prefetched regs -> packed bytes in LDS ----
        #pragma unroll
        for (int it = 0; it < LD4; ++it) {
            unsigned int u = (unsigned)v[it].x | ((unsigned)v[it].y << 8) |
                             ((unsigned)v[it].z << 16) | ((unsigned)v[it].w << 24);
            *(unsigned int*)(ws8 + (rbase + it * 32) * WSTRIDE + jcol) = u;
        }
        __syncthreads();

        // ---- issue next sub's loads; latency hides under compute below ----
        if (sub + 1 < NSUB) {
            #pragma unroll
            for (int it = 0; it < LD4; ++it) {
                int rg = min(row0 + rbase + it * 32, OUT - 1);
                v[it] = *(const int4*)(w_q + rg * IN + k0 + (sub + 1) * WSUB + jcol);
            }
        }

        float s[R], s8[R];
        #pragma unroll
        for (int r = 0; r < R; ++r) {
            float sv = (sub == 0) ? sc[r].x : (sub == 1) ? sc[r].y
                     : (sub == 2) ? sc[r].z : sc[r].w;   // sub is constant
            s[r]  = sv;
            s8[r] = -8.0f * sv;   // exact
        }

        for (int k4 = 0; k4 < WSUB / 4; ++k4) {      // 8 (rolled)
            unsigned int q[R];
            #pragma unroll
            for (int r = 0; r < R; ++r)
                q[r] = *(const unsigned int*)(ws8 + (tid + r * THREADS) * WSTRIDE + k4 * 4);

            #pragma unroll
            for (int kk = 0; kk < 4; ++kk) {
                const float4* xp = (const float4*)&xs[sub * WSUB + k4 * 4 + kk][0];
                float4 x0 = xp[0], x1 = xp[1], x2 = xp[2], x3 = xp[3];
                #pragma unroll
                for (int r = 0; r < R; ++r) {
                    // (q - 8) * s with a single rounding; byte extract is
                    // kk-constant -> v_cvt_f32_ubyte{kk}
                    float wv = fmaf((float)((q[r] >> (8 * kk)) & 0xffu), s[r], s8[r]);
                    acc[r][0]  = fmaf(wv, x0.x, acc[r][0]);
                    acc[r][1]  = fmaf(wv, x0.y, acc[r][1]);
                    acc[r][2]  = fmaf(wv, x0.z, acc[r][2]);
                    acc[r][3]  = fmaf(wv, x0.w, acc[r][3]);
                    acc[r][4]  = fmaf(wv, x1.x, acc[r][4]);
                    acc[r][5]  = fmaf(wv, x1.y, acc[r][5]);
                    acc[r][6]  = fmaf(wv, x1.z, acc[r][6]);
                    acc[r][7]  = fmaf(wv, x1.w, acc[r][7]);
                    acc[r][8]  = fmaf(wv, x2.x, acc[r][8]);
                    acc[r][9]  = fmaf(wv, x2.y, acc[r][9]);
                    acc[r][10] = fmaf(wv, x2.z, acc[r][10]);
                    acc[r][11] = fmaf(wv, x2.w, acc[r][11]);
                    acc[r][12] = fmaf(wv, x3.x, acc[r][12]);
                    acc[r][13] = fmaf(wv, x3.y, acc[r][13]);
                    acc[r][14] = fmaf(wv, x3.z, acc[r][14]);
                    acc[r][15] = fmaf(wv, x3.w, acc[r][15]);
                }
            }
        }
    }

    // ---- epilogue: bias (split 0 only) + atomic combine across splits ----
    const bool add_b = (blockIdx.y == 0);
    #pragma unroll
    for (int r = 0; r < R; ++r) {
        int rg = row0 + tid + r * THREADS;
        if (rg < OUT) {
            float b = add_b ? bias[rg] : 0.0f;
            #pragma unroll
            for (int t = 0; t < T; ++t)
                atomicAdd(out + t * OUT + rg, acc[r][t] + b);
        }
    }
}

extern "C" void kernel_launch(void* const* d_in, const int* in_sizes, int n_in,
                              void* d_out, int out_size, void* d_ws, size_t ws_size,
                              hipStream_t stream) {
    const float* x       = (const float*)d_in[0];
    const int*   w_q     = (const int*)d_in[1];
    const float* w_scale = (const float*)d_in[2];
    const float* bias    = (const float*)d_in[3];
    float*       out     = (float*)d_out;

    // Zero the (0xAA-poisoned) output; captured as a graph memset node.
    hipMemsetAsync(d_out, 0, (size_t)out_size * sizeof(float), stream);

    dim3 grid((OUT + ROWSB - 1) / ROWSB, IN / CK);   // 22 x 32 = 704 blocks
    qlinear_r2<<<grid, THREADS, 0, stream>>>(x, w_q, w_scale, bias, out);
}

// Round 2
// 351.080 us; speedup vs baseline: 4.8318x; 4.8318x over previous
//
#include <hip/hip_runtime.h>

// Q4_0 quantized linear: out[16, 11008] = x[16, 4096] @ ((w_q-8)*w_scale).T + bias
// All fp32; w_q holds int32 nibble values in [0,16).
//
// R=2 row-blocked split-K GEMV, CK=64 (64 k-splits).
// vs round-0 baseline (R=4, CK=128, 352 blocks, 110 us, 15% occupancy,
// latency-bound: both pipes idle):
//  - grid 22x64 = 1408 blocks = 5.5 blocks/CU (was 1.375). LDS 23 KiB ->
//    6 blocks/CU LDS-limit; VGPR ~84 -> not limiting. Cross-block TLP now
//    covers the barrier-fenced staging phases.
//  - NO register prefetch (round-1's 16x int4 prefetch spilled: VGPR 256,
//    3 GB scratch traffic, 14x regression). Staging is the original
//    in-loop load->pack->write with unroll 4.
// Everything else unchanged: w packed to BYTES in LDS (row stride 36 B ->
// 2-way bank aliasing = free), x chunk staged transposed for broadcast
// float4 reads, fp32 atomicAdd split-K combine (44 MB writes at 64 splits,
// minor vs 180 MB w stream), bias added by split 0.

constexpr int T       = 16;
constexpr int IN      = 4096;
constexpr int OUT     = 11008;
constexpr int NSCALE  = IN / 32;        // 128 scales per row
constexpr int THREADS = 256;
constexpr int R       = 2;              // rows per thread
constexpr int ROWSB   = THREADS * R;    // 512 rows per block
constexpr int CK      = 64;             // k per block (split-K chunk)
constexpr int WSUB    = 32;             // k per stage (== Q4_0 block size)
constexpr int NSUB    = CK / WSUB;      // 2
constexpr int WSTRIDE = 36;             // ws8 row stride bytes (32 + 4 pad -> 9 words)
constexpr int XPAD    = 20;             // xs row stride floats (80 B, 16B-aligned)

__global__ __launch_bounds__(THREADS) void qlinear_r2k64(
    const float* __restrict__ x,        // [T, IN]
    const int*   __restrict__ w_q,      // [OUT, IN]
    const float* __restrict__ w_scale,  // [OUT, NSCALE]
    const float* __restrict__ bias,     // [OUT]
    float* __restrict__ out)            // [T, OUT] (pre-zeroed)
{
    __shared__ __align__(16) float         xs[CK][XPAD];         // 5.0 KiB
    __shared__ __align__(16) unsigned char ws8[ROWSB * WSTRIDE]; // 18.0 KiB

    const int tid  = threadIdx.x;
    const int row0 = blockIdx.x * ROWSB;
    const int k0   = blockIdx.y * CK;

    // ---- stage x chunk transposed: xs[k][t] = x[t][k0+k] (coalesced) ----
    #pragma unroll
    for (int it = 0; it < CK * T / THREADS; ++it) {  // 4
        int idx = it * THREADS + tid;
        int t   = idx >> 6;          // idx / CK
        int k   = idx & (CK - 1);
        xs[k][t] = x[t * IN + k0 + k];
    }

    // ---- per-row scales for the 2 sub-blocks of this k-chunk ----
    float2 sc[R];
    #pragma unroll
    for (int r = 0; r < R; ++r) {
        int rg = min(row0 + tid + r * THREADS, OUT - 1);
        sc[r] = *(const float2*)(w_scale + rg * NSCALE + (k0 >> 5));
    }

    float acc[R][T];
    #pragma unroll
    for (int r = 0; r < R; ++r)
        #pragma unroll
        for (int t = 0; t < T; ++t) acc[r][t] = 0.0f;

    #pragma unroll
    for (int sub = 0; sub < NSUB; ++sub) {           // 2
        __syncthreads();   // protect ws8 reuse (covers xs on first trip)

        // ---- stage w tile: 512 rows x 32 ints -> packed bytes in LDS ----
        // flat int4 id f: row rr = f/8, j = f%8; lanes 0..7 read 128
        // contiguous bytes of one row (fully coalesced dwordx4 loads).
        #pragma unroll 4
        for (int it = 0; it < (ROWSB * WSUB / 4) / THREADS; ++it) {  // 16
            int f  = it * THREADS + tid;
            int rr = f >> 3;
            int j  = f & 7;
            int rg = min(row0 + rr, OUT - 1);
            const int4 v = *(const int4*)(w_q + rg * IN + k0 + sub * WSUB + j * 4);
            unsigned int u = (unsigned)v.x | ((unsigned)v.y << 8) |
                             ((unsigned)v.z << 16) | ((unsigned)v.w << 24);
            *(unsigned int*)(ws8 + rr * WSTRIDE + j * 4) = u;
        }
        __syncthreads();

        float s[R], s8[R];
        #pragma unroll
        for (int r = 0; r < R; ++r) {
            float sv = (sub == 0) ? sc[r].x : sc[r].y;   // sub is constant
            s[r]  = sv;
            s8[r] = -8.0f * sv;   // exact
        }

        for (int k4 = 0; k4 < WSUB / 4; ++k4) {      // 8 (rolled)
            unsigned int q[R];
            #pragma unroll
            for (int r = 0; r < R; ++r)
                q[r] = *(const unsigned int*)(ws8 + (tid + r * THREADS) * WSTRIDE + k4 * 4);

            #pragma unroll
            for (int kk = 0; kk < 4; ++kk) {
                const float4* xp = (const float4*)&xs[sub * WSUB + k4 * 4 + kk][0];
                float4 x0 = xp[0], x1 = xp[1], x2 = xp[2], x3 = xp[3];
                #pragma unroll
                for (int r = 0; r < R; ++r) {
                    // (q - 8) * s with a single rounding; byte extract is
                    // kk-constant -> v_cvt_f32_ubyte{kk}
                    float wv = fmaf((float)((q[r] >> (8 * kk)) & 0xffu), s[r], s8[r]);
                    acc[r][0]  = fmaf(wv, x0.x, acc[r][0]);
                    acc[r][1]  = fmaf(wv, x0.y, acc[r][1]);
                    acc[r][2]  = fmaf(wv, x0.z, acc[r][2]);
                    acc[r][3]  = fmaf(wv, x0.w, acc[r][3]);
                    acc[r][4]  = fmaf(wv, x1.x, acc[r][4]);
                    acc[r][5]  = fmaf(wv, x1.y, acc[r][5]);
                    acc[r][6]  = fmaf(wv, x1.z, acc[r][6]);
                    acc[r][7]  = fmaf(wv, x1.w, acc[r][7]);
                    acc[r][8]  = fmaf(wv, x2.x, acc[r][8]);
                    acc[r][9]  = fmaf(wv, x2.y, acc[r][9]);
                    acc[r][10] = fmaf(wv, x2.z, acc[r][10]);
                    acc[r][11] = fmaf(wv, x2.w, acc[r][11]);
                    acc[r][12] = fmaf(wv, x3.x, acc[r][12]);
                    acc[r][13] = fmaf(wv, x3.y, acc[r][13]);
                    acc[r][14] = fmaf(wv, x3.z, acc[r][14]);
                    acc[r][15] = fmaf(wv, x3.w, acc[r][15]);
                }
            }
        }
    }

    // ---- epilogue: bias (split 0 only) + atomic combine across splits ----
    const bool add_b = (blockIdx.y == 0);
    #pragma unroll
    for (int r = 0; r < R; ++r) {
        int rg = row0 + tid + r * THREADS;
        if (rg < OUT) {
            float b = add_b ? bias[rg] : 0.0f;
            #pragma unroll
            for (int t = 0; t < T; ++t)
                atomicAdd(out + t * OUT + rg, acc[r][t] + b);
        }
    }
}

extern "C" void kernel_launch(void* const* d_in, const int* in_sizes, int n_in,
                              void* d_out, int out_size, void* d_ws, size_t ws_size,
                              hipStream_t stream) {
    const float* x       = (const float*)d_in[0];
    const int*   w_q     = (const int*)d_in[1];
    const float* w_scale = (const float*)d_in[2];
    const float* bias    = (const float*)d_in[3];
    float*       out     = (float*)d_out;

    // Zero the (0xAA-poisoned) output; captured as a graph memset node.
    hipMemsetAsync(d_out, 0, (size_t)out_size * sizeof(float), stream);

    dim3 grid((OUT + ROWSB - 1) / ROWSB, IN / CK);   // 22 x 64 = 1408 blocks
    qlinear_r2k64<<<grid, THREADS, 0, stream>>>(x, w_q, w_scale, bias, out);
}